// Round 1
// baseline (127.358 us; speedup 1.0000x reference)
//
#include <hip/hip_runtime.h>

typedef __bf16 bf16;
typedef __bf16 bf16x4 __attribute__((ext_vector_type(4)));
typedef __bf16 bf16x8 __attribute__((ext_vector_type(8)));
typedef float  f32x4  __attribute__((ext_vector_type(4)));

#define MFMA16(a, b, c) __builtin_amdgcn_mfma_f32_16x16x32_bf16((a), (b), (c), 0, 0, 0)

// R21: OCCUPANCY VIA LDS SHRINK (state unchanged numerically).
//  * Theory: kernel is latency-bound (VALU 46%, MFMA 8%, HBM 1.6%); resident
//    waves capped by LDS 16896B -> 9 blocks/CU (VGPR 128 would allow 16).
//  * Change: kt tiles 5..7 of mu live in REGISTERS as B-fragments (24 VGPR);
//    their C-layout->B-frag redistribution goes through ONE 2KB rotating
//    scratch tile (same swizzle, compiler-ordered RAW/WAR). LDS 16896->12800
//    -> 12 blocks/CU; VGPR ~152 -> 3 waves/SIMD -> 12 waves/CU. +33% waves.
//  * DS op count unchanged (same 4W+2R per reg tile, readout saves 6 reads).
//  * Ledger (20 rounds): wave-per-batch, zero barriers, mu bf16 packed+XOR-
//    swizzled; s2 = W2*sumMu by 2 MFMAs (split-hi/lo sumMu); VALU epilogue
//    recomputes base fp32-exact from 6 regs via shfl. Verified negatives:
//    launch_bounds min-waves>2 => spill (R2/R4/R8); in-loop fp32 global
//    matvec => spill (R9/R12); base-by-MFMA => -50% (R18); dual-batch ILP
//    => -40% (R14); shfl-for-LDS s2 => neutral, same DS pipe (R19);
//    k-split 2-wave => -30% (R10).
#define LDS_KT 5   // kt 0..4 persistent in LDS; kt 5..7 in registers

__global__ __launch_bounds__(64, 2)
void qnet_kernel(const float* __restrict__ Xg, const float* __restrict__ Wg,
                 const float* __restrict__ W1g, const float* __restrict__ W2g,
                 const float* __restrict__ W3g, const float* __restrict__ W4g,
                 const float* __restrict__ W5g, const float* __restrict__ W6g,
                 const float* __restrict__ W7g, float* __restrict__ Outg)
{
    // 5 persistent tiles + 1 scratch tile, each 16 rows x 64 bf16 = 2048 B
    __shared__ __align__(16) bf16 muS[(LDS_KT + 1) * 16 * 64];   // 12288 B
    __shared__ __align__(16) float uS[64];                       // 256 B
    __shared__ __align__(16) float smS[64];                      // 256 B
    const int SCR = LDS_KT * 16 * 64;                            // scratch base (elems)

    const int lane = threadIdx.x;       // 0..63, one wave
    const int b    = blockIdx.x;
    const int l15  = lane & 15;
    const int quad = lane >> 4;
    const int sw   = l15 & 7;           // swizzle key: k&7 == l15&7 for k=16kt+l15

    // ---------------- per-batch vectors (6 persistent regs) ----------------
    float xv0 = Xg[b * 128 + lane], xv1 = Xg[b * 128 + 64 + lane];
    float wv0 = Wg[b * 128 + lane], wv1 = Wg[b * 128 + 64 + lane];

    float Ap = fmaxf(wv0, 0.f) + fmaxf(wv1, 0.f);
    float Bn = fmaxf(-wv0, 0.f) + fmaxf(-wv1, 0.f);
#pragma unroll
    for (int m = 1; m < 64; m <<= 1) { Ap += __shfl_xor(Ap, m); Bn += __shfl_xor(Bn, m); }

    // v3p/v3m at q=lane (exact fp32), distribute to (qt,e) epilogue layout
    float sp = 0.f, sm = 0.f;
#pragma unroll
    for (int c = 0; c < 16; ++c) {
        f32x4 w4 = *(const f32x4*)&W4g[c * 4];
        f32x4 w3 = *(const f32x4*)&W3g[lane * 64 + c * 4];
#pragma unroll
        for (int e = 0; e < 4; ++e) {
            sp += fmaxf(w4[e], 0.f) * w3[e];
            sm += fmaxf(-w4[e], 0.f) * w3[e];
        }
    }
    float w1C[16], v3pC[16], v3mC[16];
#pragma unroll
    for (int qt = 0; qt < 4; ++qt) {
        f32x4 w1v = *(const f32x4*)&W1g[qt * 16 + quad * 4];
#pragma unroll
        for (int e = 0; e < 4; ++e) {
            const int q = qt * 16 + quad * 4 + e;
            v3pC[qt * 4 + e] = __shfl(sp, q);
            v3mC[qt * 4 + e] = __shfl(sm, q);
            w1C[qt * 4 + e]  = w1v[e];
        }
    }

    // u[p=lane] = W5b @ W7[:,p] -> uS (wave-private LDS)
    {
        float u = 0.f;
#pragma unroll
        for (int c = 0; c < 16; ++c) {
            f32x4 w5v = *(const f32x4*)&W5g[64 + c * 4];
#pragma unroll
            for (int e = 0; e < 4; ++e) u += w5v[e] * W7g[(c * 4 + e) * 64 + lane];
        }
        uS[lane] = u;
    }

    // W2 A-fragments (bf16 hi only)
    bf16x8 w2h[4][2];
#pragma unroll
    for (int qt = 0; qt < 4; ++qt)
#pragma unroll
        for (int s = 0; s < 2; ++s) {
            const float* src = &W2g[(qt * 16 + l15) * 64 + s * 32 + quad * 8];
            f32x4 f0 = *(const f32x4*)src;
            f32x4 f1 = *(const f32x4*)(src + 4);
            bf16x8 h;
#pragma unroll
            for (int e = 0; e < 4; ++e) { h[e] = (bf16)f0[e]; h[4 + e] = (bf16)f1[e]; }
            w2h[qt][s] = h;
        }

    // register-resident mu B-fragments for kt = 5..7 (24 VGPRs)
    bf16x8 mr0[8 - LDS_KT], mr1[8 - LDS_KT];

    // ---------------- mu1 = relu(base), exact fp32; accumulate smv ----------------
    float smv[16];
#pragma unroll
    for (int i = 0; i < 16; ++i) smv[i] = 0.f;
#pragma unroll
    for (int kt = 0; kt < 8; ++kt) {
        const int src = (kt & 3) * 16 + l15;
        float xs_ = __shfl((kt < 4) ? xv0 : xv1, src);
        float ws_ = __shfl((kt < 4) ? wv0 : wv1, src);
        float ap_ = Ap - fmaxf(ws_, 0.f);
        float bn_ = Bn - fmaxf(-ws_, 0.f);
        const int row = (kt < LDS_KT) ? (kt * 16 + l15) * 64 : (SCR + l15 * 64);
#pragma unroll
        for (int qt = 0; qt < 4; ++qt) {
            bf16x4 h;
#pragma unroll
            for (int e = 0; e < 4; ++e) {
                float t = fmaf(xs_, w1C[qt * 4 + e],
                          fmaf(ap_, v3pC[qt * 4 + e], bn_ * v3mC[qt * 4 + e]));
                float v = fmaxf(t, 0.f);
                smv[qt * 4 + e] += v;
                h[e] = (bf16)v;
            }
            *(bf16x4*)&muS[row + ((2 * qt + (quad >> 1)) ^ sw) * 8 + 4 * (quad & 1)] = h;
        }
        if (kt >= LDS_KT) {   // redistribute scratch -> registers (B-frag form)
            mr0[kt - LDS_KT] = *(const bf16x8*)&muS[row + ((quad) ^ sw) * 8];
            mr1[kt - LDS_KT] = *(const bf16x8*)&muS[row + ((4 + quad) ^ sw) * 8];
        }
    }

    // ---------------- 3 iterations, zero barriers ----------------
    const f32x4 zero4 = {0.f, 0.f, 0.f, 0.f};
    for (int it = 0; it < 3; ++it) {
        // sumMu: l15 butterfly + publish to smS
#pragma unroll
        for (int m = 1; m <= 8; m <<= 1)
#pragma unroll
            for (int i = 0; i < 16; ++i) smv[i] += __shfl_xor(smv[i], m);
        if (l15 == 0) {
#pragma unroll
            for (int qt = 0; qt < 4; ++qt) {
                f32x4 v = {smv[qt * 4], smv[qt * 4 + 1], smv[qt * 4 + 2], smv[qt * 4 + 3]};
                *(f32x4*)&smS[qt * 16 + quad * 4] = v;
            }
        }
        // s2 = W2·sumMu by MFMA: lean frag build (Sh col 0, Sl col 1)
        bf16x8 bs0, bs1;
        {
            f32x4 pA = *(const f32x4*)&smS[quad * 8];
            f32x4 pB = *(const f32x4*)&smS[quad * 8 + 4];
#pragma unroll
            for (int e = 0; e < 4; ++e) {
                bf16 h = (bf16)pA[e];
                bs0[e] = (l15 == 0) ? h : ((l15 == 1) ? (bf16)(pA[e] - (float)h) : (bf16)0.f);
                bf16 g = (bf16)pB[e];
                bs0[4 + e] = (l15 == 0) ? g : ((l15 == 1) ? (bf16)(pB[e] - (float)g) : (bf16)0.f);
            }
            pA = *(const f32x4*)&smS[32 + quad * 8];
            pB = *(const f32x4*)&smS[32 + quad * 8 + 4];
#pragma unroll
            for (int e = 0; e < 4; ++e) {
                bf16 h = (bf16)pA[e];
                bs1[e] = (l15 == 0) ? h : ((l15 == 1) ? (bf16)(pA[e] - (float)h) : (bf16)0.f);
                bf16 g = (bf16)pB[e];
                bs1[4 + e] = (l15 == 0) ? g : ((l15 == 1) ? (bf16)(pB[e] - (float)g) : (bf16)0.f);
            }
        }
        f32x4 s2q[4];
#pragma unroll
        for (int qt = 0; qt < 4; ++qt) {
            f32x4 a = MFMA16(w2h[qt][0], bs0, zero4);
            a = MFMA16(w2h[qt][1], bs1, a);
#pragma unroll
            for (int e = 0; e < 4; ++e)
                s2q[qt][e] = __shfl(a[e], quad * 16) + __shfl(a[e], quad * 16 + 1);
        }

        // main pass: 64 MFMAs + fused epilogue (base recomputed fp32-exact,
        // per-kt scalars recomputed via shfl -- no persistent arrays)
#pragma unroll
        for (int i = 0; i < 16; ++i) smv[i] = 0.f;
#pragma unroll
        for (int kt = 0; kt < 8; ++kt) {
            const int src = (kt & 3) * 16 + l15;
            float xs_ = __shfl((kt < 4) ? xv0 : xv1, src);
            float ws_ = __shfl((kt < 4) ? wv0 : wv1, src);
            float ap_ = Ap - fmaxf(ws_, 0.f);
            float bn_ = Bn - fmaxf(-ws_, 0.f);
            const int row = (kt < LDS_KT) ? (kt * 16 + l15) * 64 : (SCR + l15 * 64);
            bf16x8 m0, m1;
            if (kt < LDS_KT) {
                m0 = *(const bf16x8*)&muS[row + ((quad) ^ sw) * 8];
                m1 = *(const bf16x8*)&muS[row + ((4 + quad) ^ sw) * 8];
            } else {
                m0 = mr0[kt - LDS_KT];
                m1 = mr1[kt - LDS_KT];
            }
#pragma unroll
            for (int qt = 0; qt < 4; ++qt) {
                f32x4 a = MFMA16(w2h[qt][0], m0, zero4);
                a = MFMA16(w2h[qt][1], m1, a);
                bf16x4 h;
#pragma unroll
                for (int e = 0; e < 4; ++e) {
                    float t = fmaf(xs_, w1C[qt * 4 + e], s2q[qt][e]);
                    t = fmaf(ap_, v3pC[qt * 4 + e], t);
                    t = fmaf(bn_, v3mC[qt * 4 + e], t);
                    float v = fmaxf(t - a[e], 0.f);
                    smv[qt * 4 + e] += v;
                    h[e] = (bf16)v;
                }
                *(bf16x4*)&muS[row + ((2 * qt + (quad >> 1)) ^ sw) * 8 + 4 * (quad & 1)] = h;
            }
            if (kt >= LDS_KT) {   // new B-frags back into registers
                mr0[kt - LDS_KT] = *(const bf16x8*)&muS[row + ((quad) ^ sw) * 8];
                mr1[kt - LDS_KT] = *(const bf16x8*)&muS[row + ((4 + quad) ^ sw) * 8];
            }
        }
    }

    // ---------------- readout (wave-internal) ----------------
#pragma unroll
    for (int m = 1; m <= 8; m <<= 1)
#pragma unroll
        for (int i = 0; i < 16; ++i) smv[i] += __shfl_xor(smv[i], m);
    if (l15 == 0) {
#pragma unroll
        for (int qt = 0; qt < 4; ++qt) {
            f32x4 v = {smv[qt * 4], smv[qt * 4 + 1], smv[qt * 4 + 2], smv[qt * 4 + 3]};
            *(f32x4*)&smS[qt * 16 + quad * 4] = v;
        }
    }

    float pl = 0.f;
#pragma unroll
    for (int c = 0; c < 16; ++c) {
        f32x4 sv = *(const f32x4*)&smS[c * 4];
        f32x4 w6 = *(const f32x4*)&W6g[lane * 64 + c * 4];
#pragma unroll
        for (int e = 0; e < 4; ++e) pl = fmaf(sv[e], w6[e], pl);
    }
    float qa = fmaxf(pl, 0.f) * W5g[lane];
#pragma unroll
    for (int m = 1; m < 64; m <<= 1) qa += __shfl_xor(qa, m);

    f32x4 uf[2][2];
#pragma unroll
    for (int s = 0; s < 2; ++s) {
        uf[s][0] = *(const f32x4*)&uS[s * 32 + quad * 8];
        uf[s][1] = *(const f32x4*)&uS[s * 32 + quad * 8 + 4];
    }

    float res[8];
#pragma unroll
    for (int kt = 0; kt < 8; ++kt) {
        bf16x8 m0, m1;
        if (kt < LDS_KT) {
            const int row = (kt * 16 + l15) * 64;
            m0 = *(const bf16x8*)&muS[row + ((quad) ^ sw) * 8];
            m1 = *(const bf16x8*)&muS[row + ((4 + quad) ^ sw) * 8];
        } else {
            m0 = mr0[kt - LDS_KT];
            m1 = mr1[kt - LDS_KT];
        }
        float r = 0.f;
#pragma unroll
        for (int j = 0; j < 4; ++j) {
            r = fmaf((float)m0[j],     uf[0][0][j], r);
            r = fmaf((float)m0[4 + j], uf[0][1][j], r);
            r = fmaf((float)m1[j],     uf[1][0][j], r);
            r = fmaf((float)m1[4 + j], uf[1][1][j], r);
        }
        r += __shfl_xor(r, 16); r += __shfl_xor(r, 32);
        res[kt] = r;
    }
    float rA0 = (quad & 1) ? res[1] : res[0];
    float rA1 = (quad & 1) ? res[3] : res[2];
    float rA  = (quad & 2) ? rA1 : rA0;
    float rB0 = (quad & 1) ? res[5] : res[4];
    float rB1 = (quad & 1) ? res[7] : res[6];
    float rB  = (quad & 2) ? rB1 : rB0;
    Outg[b * 128 + lane]      = qa + rA;   // k = lane       (kt = quad)
    Outg[b * 128 + 64 + lane] = qa + rB;   // k = lane + 64  (kt = quad + 4)
}

extern "C" void kernel_launch(void* const* d_in, const int* in_sizes, int n_in,
                              void* d_out, int out_size, void* d_ws, size_t ws_size,
                              hipStream_t stream) {
    (void)n_in; (void)d_ws; (void)ws_size; (void)out_size;
    const int B = in_sizes[0] >> 7;   // 4096
    qnet_kernel<<<B, 64, 0, stream>>>(
        (const float*)d_in[0], (const float*)d_in[1], (const float*)d_in[2],
        (const float*)d_in[3], (const float*)d_in[4], (const float*)d_in[5],
        (const float*)d_in[6], (const float*)d_in[7], (const float*)d_in[8],
        (float*)d_out);
}

// Round 2
// 115.872 us; speedup vs baseline: 1.0991x; 1.0991x over previous
//
#include <hip/hip_runtime.h>

typedef __bf16 bf16;
typedef __bf16 bf16x4 __attribute__((ext_vector_type(4)));
typedef __bf16 bf16x8 __attribute__((ext_vector_type(8)));
typedef float  f32x2  __attribute__((ext_vector_type(2)));
typedef float  f32x4  __attribute__((ext_vector_type(4)));

#define MFMA16(a, b, c) __builtin_amdgcn_mfma_f32_16x16x32_bf16((a), (b), (c), 0, 0, 0)

// R22: ISSUE-SLOT DIET. R21 proved occupancy is NOT the lever (LDS 12800,
// 12 blocks/CU possible -> zero perf change, occupancy pinned ~17%). Model:
// two ~50% pipes (VALU 47%, DS ~50% from ~730 DS-ops/wave) + serial latency.
// Changes vs R17 frontier (mr-tiles of R21 reverted -- neutral + spilled):
//  1. DPP rotate-add butterflies (v_add_f32_dpp row_ror:1/2/4/8) replace all
//     4 smv butterflies: -256 ds_bpermute/wave, DS latency chain -> VALU.
//  2. s2 by all-column broadcast hi/lo frags: 4 MFMAs/qt, no shfl-sum:
//     -96 ds_bpermute, -cndmask build.
//  3. f32x2 packed epilogue (v_pk_fma_f32 path): ~40% fewer VALU ops in the
//     base-recompute/relu/accum and mu1 init.
// Ledger: wave-per-batch, zero barriers, mu bf16 128x64 packed+XOR-swizzled
// (16.4KB); VALU epilogue recomputes base fp32-exact from 6 regs via shfl.
// Negatives: launch_bounds min-waves>2 spill (R2/4/8); in-loop fp32 global
// matvec spill (R9/12); base-by-MFMA -50% (R18); dual-batch -40% (R14);
// k-split -30% (R10); LDS-shrink-for-occupancy neutral (R21).

template<int CTRL>
__device__ __forceinline__ float dpp_add(float v) {
    int t = __builtin_amdgcn_update_dpp(0, __float_as_int(v), CTRL, 0xF, 0xF, false);
    return v + __int_as_float(t);
}

// full 16-lane-row sum: after ror 1,2,4,8 every lane holds the row total
__device__ __forceinline__ void bfly16(f32x2* s) {
#pragma unroll
    for (int i = 0; i < 8; ++i) { s[i][0] = dpp_add<0x121>(s[i][0]); s[i][1] = dpp_add<0x121>(s[i][1]); }
#pragma unroll
    for (int i = 0; i < 8; ++i) { s[i][0] = dpp_add<0x122>(s[i][0]); s[i][1] = dpp_add<0x122>(s[i][1]); }
#pragma unroll
    for (int i = 0; i < 8; ++i) { s[i][0] = dpp_add<0x124>(s[i][0]); s[i][1] = dpp_add<0x124>(s[i][1]); }
#pragma unroll
    for (int i = 0; i < 8; ++i) { s[i][0] = dpp_add<0x128>(s[i][0]); s[i][1] = dpp_add<0x128>(s[i][1]); }
}

__device__ __forceinline__ f32x2 fma2(f32x2 a, f32x2 b, f32x2 c) {
    return __builtin_elementwise_fma(a, b, c);
}
__device__ __forceinline__ f32x2 max2(f32x2 a, f32x2 b) {
    return __builtin_elementwise_max(a, b);
}

__global__ __launch_bounds__(64, 2)
void qnet_kernel(const float* __restrict__ Xg, const float* __restrict__ Wg,
                 const float* __restrict__ W1g, const float* __restrict__ W2g,
                 const float* __restrict__ W3g, const float* __restrict__ W4g,
                 const float* __restrict__ W5g, const float* __restrict__ W6g,
                 const float* __restrict__ W7g, float* __restrict__ Outg)
{
    __shared__ __align__(16) bf16 muS[128 * 64];   // 16384 B, packed + swizzled
    __shared__ __align__(16) float uS[64];         // 256 B
    __shared__ __align__(16) float smS[64];        // 256 B  sumMu broadcast

    const int lane = threadIdx.x;       // 0..63, one wave
    const int b    = blockIdx.x;
    const int l15  = lane & 15;
    const int quad = lane >> 4;
    const int sw   = l15 & 7;           // swizzle key: k&7 == l15&7 for k=16kt+l15

    // ---------------- per-batch vectors (6 persistent regs) ----------------
    float xv0 = Xg[b * 128 + lane], xv1 = Xg[b * 128 + 64 + lane];
    float wv0 = Wg[b * 128 + lane], wv1 = Wg[b * 128 + 64 + lane];

    float Ap = fmaxf(wv0, 0.f) + fmaxf(wv1, 0.f);
    float Bn = fmaxf(-wv0, 0.f) + fmaxf(-wv1, 0.f);
#pragma unroll
    for (int m = 1; m < 64; m <<= 1) { Ap += __shfl_xor(Ap, m); Bn += __shfl_xor(Bn, m); }

    // v3p/v3m at q=lane (exact fp32), distribute to (qt,pair) epilogue layout
    float sp = 0.f, sm = 0.f;
#pragma unroll
    for (int c = 0; c < 16; ++c) {
        f32x4 w4 = *(const f32x4*)&W4g[c * 4];
        f32x4 w3 = *(const f32x4*)&W3g[lane * 64 + c * 4];
#pragma unroll
        for (int e = 0; e < 4; ++e) {
            sp += fmaxf(w4[e], 0.f) * w3[e];
            sm += fmaxf(-w4[e], 0.f) * w3[e];
        }
    }
    f32x2 w1P[4][2], v3pP[4][2], v3mP[4][2];
#pragma unroll
    for (int qt = 0; qt < 4; ++qt) {
        f32x4 w1v = *(const f32x4*)&W1g[qt * 16 + quad * 4];
#pragma unroll
        for (int e = 0; e < 4; ++e) {
            const int q = qt * 16 + quad * 4 + e;
            v3pP[qt][e >> 1][e & 1] = __shfl(sp, q);
            v3mP[qt][e >> 1][e & 1] = __shfl(sm, q);
            w1P[qt][e >> 1][e & 1]  = w1v[e];
        }
    }

    // u[p=lane] = W5b @ W7[:,p] -> uS (wave-private LDS)
    {
        float u = 0.f;
#pragma unroll
        for (int c = 0; c < 16; ++c) {
            f32x4 w5v = *(const f32x4*)&W5g[64 + c * 4];
#pragma unroll
            for (int e = 0; e < 4; ++e) u += w5v[e] * W7g[(c * 4 + e) * 64 + lane];
        }
        uS[lane] = u;
    }

    // W2 A-fragments (bf16 hi only)
    bf16x8 w2h[4][2];
#pragma unroll
    for (int qt = 0; qt < 4; ++qt)
#pragma unroll
        for (int s = 0; s < 2; ++s) {
            const float* src = &W2g[(qt * 16 + l15) * 64 + s * 32 + quad * 8];
            f32x4 f0 = *(const f32x4*)src;
            f32x4 f1 = *(const f32x4*)(src + 4);
            bf16x8 h;
#pragma unroll
            for (int e = 0; e < 4; ++e) { h[e] = (bf16)f0[e]; h[4 + e] = (bf16)f1[e]; }
            w2h[qt][s] = h;
        }

    const f32x2 zz = {0.f, 0.f};

    // ---------------- mu1 = relu(base), exact fp32; accumulate smv ----------------
    f32x2 smv2[8];
#pragma unroll
    for (int i = 0; i < 8; ++i) smv2[i] = zz;
#pragma unroll
    for (int kt = 0; kt < 8; ++kt) {
        const int src = (kt & 3) * 16 + l15;
        float xs_ = __shfl((kt < 4) ? xv0 : xv1, src);
        float ws_ = __shfl((kt < 4) ? wv0 : wv1, src);
        f32x2 xs2 = {xs_, xs_};
        float ap_ = Ap - fmaxf(ws_, 0.f);
        float bn_ = Bn - fmaxf(-ws_, 0.f);
        f32x2 ap2 = {ap_, ap_}, bn2 = {bn_, bn_};
        const int row = (kt * 16 + l15) * 64;
#pragma unroll
        for (int qt = 0; qt < 4; ++qt) {
            f32x2 t01 = fma2(ap2, v3pP[qt][0], bn2 * v3mP[qt][0]);
            t01 = fma2(xs2, w1P[qt][0], t01);
            f32x2 v01 = max2(t01, zz);
            f32x2 t23 = fma2(ap2, v3pP[qt][1], bn2 * v3mP[qt][1]);
            t23 = fma2(xs2, w1P[qt][1], t23);
            f32x2 v23 = max2(t23, zz);
            smv2[qt * 2]     += v01;
            smv2[qt * 2 + 1] += v23;
            bf16x4 h = {(bf16)v01[0], (bf16)v01[1], (bf16)v23[0], (bf16)v23[1]};
            *(bf16x4*)&muS[row + ((2 * qt + (quad >> 1)) ^ sw) * 8 + 4 * (quad & 1)] = h;
        }
    }

    // ---------------- 3 iterations, zero barriers ----------------
    const f32x4 zero4 = {0.f, 0.f, 0.f, 0.f};
    for (int it = 0; it < 3; ++it) {
        // sumMu: DPP ror butterfly (all lanes end with the 16-row total)
        bfly16(smv2);
        if (l15 == 0) {
#pragma unroll
            for (int qt = 0; qt < 4; ++qt) {
                f32x4 v = {smv2[qt * 2][0], smv2[qt * 2][1],
                           smv2[qt * 2 + 1][0], smv2[qt * 2 + 1][1]};
                *(f32x4*)&smS[qt * 16 + quad * 4] = v;
            }
        }
        // s2 = W2·sumMu: hi/lo split, every l15 column broadcasts the value
        // -> 4 MFMAs per qt give s2 at every lane, zero shfl.
        bf16x8 bh0, bl0, bh1, bl1;
        {
            f32x4 pA = *(const f32x4*)&smS[quad * 8];
            f32x4 pB = *(const f32x4*)&smS[quad * 8 + 4];
#pragma unroll
            for (int e = 0; e < 4; ++e) {
                bf16 h = (bf16)pA[e]; bh0[e] = h;     bl0[e] = (bf16)(pA[e] - (float)h);
                bf16 g = (bf16)pB[e]; bh0[4 + e] = g; bl0[4 + e] = (bf16)(pB[e] - (float)g);
            }
            pA = *(const f32x4*)&smS[32 + quad * 8];
            pB = *(const f32x4*)&smS[32 + quad * 8 + 4];
#pragma unroll
            for (int e = 0; e < 4; ++e) {
                bf16 h = (bf16)pA[e]; bh1[e] = h;     bl1[e] = (bf16)(pA[e] - (float)h);
                bf16 g = (bf16)pB[e]; bh1[4 + e] = g; bl1[4 + e] = (bf16)(pB[e] - (float)g);
            }
        }
        f32x2 s2p[4][2];
#pragma unroll
        for (int qt = 0; qt < 4; ++qt) {
            f32x4 a = MFMA16(w2h[qt][0], bh0, zero4);
            a = MFMA16(w2h[qt][1], bh1, a);
            a = MFMA16(w2h[qt][0], bl0, a);
            a = MFMA16(w2h[qt][1], bl1, a);
            s2p[qt][0] = __builtin_shufflevector(a, a, 0, 1);
            s2p[qt][1] = __builtin_shufflevector(a, a, 2, 3);
        }

        // main pass: 64 MFMAs + packed-fp32 fused epilogue
#pragma unroll
        for (int i = 0; i < 8; ++i) smv2[i] = zz;
#pragma unroll
        for (int kt = 0; kt < 8; ++kt) {
            const int src = (kt & 3) * 16 + l15;
            float xs_ = __shfl((kt < 4) ? xv0 : xv1, src);
            float ws_ = __shfl((kt < 4) ? wv0 : wv1, src);
            f32x2 xs2 = {xs_, xs_};
            float ap_ = Ap - fmaxf(ws_, 0.f);
            float bn_ = Bn - fmaxf(-ws_, 0.f);
            f32x2 ap2 = {ap_, ap_}, bn2 = {bn_, bn_};
            const int row = (kt * 16 + l15) * 64;
            bf16x8 m0 = *(const bf16x8*)&muS[row + ((quad) ^ sw) * 8];
            bf16x8 m1 = *(const bf16x8*)&muS[row + ((4 + quad) ^ sw) * 8];
#pragma unroll
            for (int qt = 0; qt < 4; ++qt) {
                f32x4 a = MFMA16(w2h[qt][0], m0, zero4);
                a = MFMA16(w2h[qt][1], m1, a);
                f32x2 a01 = __builtin_shufflevector(a, a, 0, 1);
                f32x2 a23 = __builtin_shufflevector(a, a, 2, 3);
                f32x2 t01 = fma2(xs2, w1P[qt][0], s2p[qt][0]);
                t01 = fma2(ap2, v3pP[qt][0], t01);
                t01 = fma2(bn2, v3mP[qt][0], t01);
                f32x2 v01 = max2(t01 - a01, zz);
                f32x2 t23 = fma2(xs2, w1P[qt][1], s2p[qt][1]);
                t23 = fma2(ap2, v3pP[qt][1], t23);
                t23 = fma2(bn2, v3mP[qt][1], t23);
                f32x2 v23 = max2(t23 - a23, zz);
                smv2[qt * 2]     += v01;
                smv2[qt * 2 + 1] += v23;
                bf16x4 h = {(bf16)v01[0], (bf16)v01[1], (bf16)v23[0], (bf16)v23[1]};
                *(bf16x4*)&muS[row + ((2 * qt + (quad >> 1)) ^ sw) * 8 + 4 * (quad & 1)] = h;
            }
        }
    }

    // ---------------- readout (wave-internal) ----------------
    bfly16(smv2);
    if (l15 == 0) {
#pragma unroll
        for (int qt = 0; qt < 4; ++qt) {
            f32x4 v = {smv2[qt * 2][0], smv2[qt * 2][1],
                       smv2[qt * 2 + 1][0], smv2[qt * 2 + 1][1]};
            *(f32x4*)&smS[qt * 16 + quad * 4] = v;
        }
    }

    float pl = 0.f;
#pragma unroll
    for (int c = 0; c < 16; ++c) {
        f32x4 sv = *(const f32x4*)&smS[c * 4];
        f32x4 w6 = *(const f32x4*)&W6g[lane * 64 + c * 4];
#pragma unroll
        for (int e = 0; e < 4; ++e) pl = fmaf(sv[e], w6[e], pl);
    }
    float qa = fmaxf(pl, 0.f) * W5g[lane];
#pragma unroll
    for (int m = 1; m < 64; m <<= 1) qa += __shfl_xor(qa, m);

    f32x4 uf[2][2];
#pragma unroll
    for (int s = 0; s < 2; ++s) {
        uf[s][0] = *(const f32x4*)&uS[s * 32 + quad * 8];
        uf[s][1] = *(const f32x4*)&uS[s * 32 + quad * 8 + 4];
    }

    float res[8];
#pragma unroll
    for (int kt = 0; kt < 8; ++kt) {
        const int row = (kt * 16 + l15) * 64;
        bf16x8 m0 = *(const bf16x8*)&muS[row + ((quad) ^ sw) * 8];
        bf16x8 m1 = *(const bf16x8*)&muS[row + ((4 + quad) ^ sw) * 8];
        float r = 0.f;
#pragma unroll
        for (int j = 0; j < 4; ++j) {
            r = fmaf((float)m0[j],     uf[0][0][j], r);
            r = fmaf((float)m0[4 + j], uf[0][1][j], r);
            r = fmaf((float)m1[j],     uf[1][0][j], r);
            r = fmaf((float)m1[4 + j], uf[1][1][j], r);
        }
        r += __shfl_xor(r, 16); r += __shfl_xor(r, 32);
        res[kt] = r;
    }
    float rA0 = (quad & 1) ? res[1] : res[0];
    float rA1 = (quad & 1) ? res[3] : res[2];
    float rA  = (quad & 2) ? rA1 : rA0;
    float rB0 = (quad & 1) ? res[5] : res[4];
    float rB1 = (quad & 1) ? res[7] : res[6];
    float rB  = (quad & 2) ? rB1 : rB0;
    Outg[b * 128 + lane]      = qa + rA;   // k = lane       (kt = quad)
    Outg[b * 128 + 64 + lane] = qa + rB;   // k = lane + 64  (kt = quad + 4)
}

extern "C" void kernel_launch(void* const* d_in, const int* in_sizes, int n_in,
                              void* d_out, int out_size, void* d_ws, size_t ws_size,
                              hipStream_t stream) {
    (void)n_in; (void)d_ws; (void)ws_size; (void)out_size;
    const int B = in_sizes[0] >> 7;   // 4096
    qnet_kernel<<<B, 64, 0, stream>>>(
        (const float*)d_in[0], (const float*)d_in[1], (const float*)d_in[2],
        (const float*)d_in[3], (const float*)d_in[4], (const float*)d_in[5],
        (const float*)d_in[6], (const float*)d_in[7], (const float*)d_in[8],
        (float*)d_out);
}